// Round 5
// baseline (424.709 us; speedup 1.0000x reference)
//
#include <hip/hip_runtime.h>
#include <hip/hip_bf16.h>
#include <cmath>

// Problem constants
#define B_DIM 4
#define T_DIM 2048
#define D_DIM 1024
#define M_DIM 8192          // B*T
#define KP    2048          // physical K per activation row: [hi|lo]
#define NT    64            // K'=2048 / BK=32 K-tiles

#define NCH   64            // scan chunks
#define CHL   32            // T / NCH

using bf16 = __hip_bfloat16;
typedef __attribute__((ext_vector_type(8))) short frag8;   // 8 bf16 (4 VGPRs)
typedef __attribute__((ext_vector_type(4))) float f32x4;   // MFMA accumulator

// ---------------- workspace layout (bytes) ----------------
#define XS_OFF   0L
#define WIN_OFF  33554432L
#define WSS_OFF  37748736L
#define WOS_OFF  39845888L
#define GATE_OFF 41943040L
#define VS_OFF   75497472L
#define AF_OFF   109051904L
#define BF_OFF   142606336L
#define ACH_OFF  176160768L
#define BCH_OFF  177209344L
#define CAR_OFF  178257920L

// ---------------- hi/lo split convert for activations (4 f32/thread) ----------------
__global__ void split_kernel(const float* __restrict__ src, bf16* __restrict__ dst, long total4) {
    long i4 = (long)blockIdx.x * blockDim.x + threadIdx.x;
    if (i4 >= total4) return;
    long i = i4 * 4;
    const float4 v = *(const float4*)&src[i];
    long r = i >> 10;
    int  c = (int)(i & 1023);
    ushort hi[4], lo[4];
    const float vv[4] = {v.x, v.y, v.z, v.w};
#pragma unroll
    for (int j = 0; j < 4; ++j) {
        bf16 h = __float2bfloat16(vv[j]);
        hi[j] = *(ushort*)&h;
        bf16 l2 = __float2bfloat16(vv[j] - __bfloat162float(h));
        lo[j] = *(ushort*)&l2;
    }
    *(ushort4*)&dst[r * KP + c]        = make_ushort4(hi[0], hi[1], hi[2], hi[3]);
    *(ushort4*)&dst[r * KP + c + 1024] = make_ushort4(lo[0], lo[1], lo[2], lo[3]);
}

// weights: plain RN-bf16 convert, [N][1024] hi-only
__global__ void split_hi_kernel(const float* __restrict__ src, bf16* __restrict__ dst, long total4) {
    long i4 = (long)blockIdx.x * blockDim.x + threadIdx.x;
    if (i4 >= total4) return;
    long i = i4 * 4;
    const float4 v = *(const float4*)&src[i];
    bf16 h0 = __float2bfloat16(v.x), h1 = __float2bfloat16(v.y);
    bf16 h2 = __float2bfloat16(v.z), h3 = __float2bfloat16(v.w);
    *(ushort4*)&dst[i] = make_ushort4(*(ushort*)&h0, *(ushort*)&h1, *(ushort*)&h2, *(ushort*)&h3);
}

// ---------------- 256x256 / BK=32 / 8-wave / ring-4 counted-vmcnt GEMM ----------------
// C[m,n] = sum_{k'=0..2047} A[m,k'] * Bhi[n, k' & 1023]
//   A physical [M][2048] = [hi|lo] -> (hi_a + lo_a) . hi_b
// LDS: 4-slot ring per operand, each slot 256x32 bf16 (16 KiB) -> 128 KiB total.
// Swizzle (T2): element col c stored at c ^ (g(r)<<3), g(r)=((r&3)^((r>>2)&3));
//   applied as pre-swizzled GLOBAL source col (linear global_load_lds dest, rule #21)
//   + swizzled ds_read col. Involution, 16B-aligned.
// Schedule per K-tile kt (slot kt&3): two phases of {ds_read; stage 2 loads of
//   tile kt+3; barrier; setprio(1); 16 MFMA; setprio(0); [vmcnt]; barrier}.
// vmcnt(8) at tile boundary = tiles kt+2,kt+3 still in flight (never 0 in steady state).
#define AS1 const __attribute__((address_space(1))) void*
#define AS3 __attribute__((address_space(3))) void*

template<int EPI>
__global__ __launch_bounds__(512, 2)
void gemm8p(const bf16* __restrict__ A, const bf16* __restrict__ Bw,
            const float* __restrict__ bias,
            const float* __restrict__ gatef_in,
            const float* __restrict__ x_in,
            float* __restrict__ out0, float* __restrict__ out1,
            bf16* __restrict__ outv)
{
    __shared__ bf16 As[4][8192];   // [slot][256*32]
    __shared__ bf16 Bs[4][8192];
    const int t   = threadIdx.x;
    const int l   = t & 63;
    const int wid = t >> 6;
    const int wr  = wid >> 2;      // 0..1
    const int wc  = wid & 3;       // 0..3
    const int bm  = blockIdx.x;
    const int bn  = blockIdx.y;

    f32x4 acc[8][4] = {};

    // stage addressing: thread t writes LDS elems [t*8, t*8+8) (+4096 for 2nd load)
    // -> (r = t>>2 (+128), c = (t&3)*8); source col pre-swizzled.
    const int sr  = t >> 2;
    const int sg  = ((t >> 2) ^ (t >> 4)) & 3;
    const int scS = ((t & 3) * 8) ^ (sg << 3);
    const bf16* Ab = A  + ((long)bm * 256 + sr) * KP   + scS;
    const bf16* Bb = Bw + ((long)bn * 256 + sr) * 1024 + scS;

    // reader: swizzled k-chunk (row&3 = l&3, (row>>2)&3 = (l>>2)&3 since bases %16==0)
    const int rk    = ((((l >> 4) & 3) ^ (l & 3) ^ ((l >> 2) & 3)) << 3);
    const int rowA0 = wr * 128 + (l & 15);
    const int rowB0 = wc * 64  + (l & 15);

#define STAGE_A(kt) {                                                            \
    const int  s_ = (kt) & 3;                                                    \
    const long ka = (long)(kt) * 32;                                             \
    __builtin_amdgcn_global_load_lds((AS1)(Ab + ka),            (AS3)&As[s_][t * 8],        16, 0, 0); \
    __builtin_amdgcn_global_load_lds((AS1)(Ab + 128 * KP + ka), (AS3)&As[s_][4096 + t * 8], 16, 0, 0); \
}
#define STAGE_B(kt) {                                                            \
    const int  s_ = (kt) & 3;                                                    \
    const long kb = (long)((kt) & 31) * 32;                                      \
    __builtin_amdgcn_global_load_lds((AS1)(Bb + kb),              (AS3)&Bs[s_][t * 8],        16, 0, 0); \
    __builtin_amdgcn_global_load_lds((AS1)(Bb + 128 * 1024 + kb), (AS3)&Bs[s_][4096 + t * 8], 16, 0, 0); \
}

    // prologue: tiles 0,1,2 in flight (12 loads/thread)
    STAGE_A(0); STAGE_B(0);
    STAGE_A(1); STAGE_B(1);
    STAGE_A(2); STAGE_B(2);
    asm volatile("s_waitcnt vmcnt(8)" ::: "memory");   // tile 0 landed (per-wave)
    __builtin_amdgcn_s_barrier();                      // ...landed for ALL waves
    asm volatile("" ::: "memory");

    for (int kt = 0; kt < NT; ++kt) {
        const int s = kt & 3;
        // ---- phase A: ds_read B(0..3)+A(0..3); stage A-part of kt+3 ----
        frag8 fb0 = *(const frag8*)&Bs[s][(rowB0     ) * 32 + rk];
        frag8 fb1 = *(const frag8*)&Bs[s][(rowB0 + 16) * 32 + rk];
        frag8 fb2 = *(const frag8*)&Bs[s][(rowB0 + 32) * 32 + rk];
        frag8 fb3 = *(const frag8*)&Bs[s][(rowB0 + 48) * 32 + rk];
        frag8 fa0 = *(const frag8*)&As[s][(rowA0     ) * 32 + rk];
        frag8 fa1 = *(const frag8*)&As[s][(rowA0 + 16) * 32 + rk];
        frag8 fa2 = *(const frag8*)&As[s][(rowA0 + 32) * 32 + rk];
        frag8 fa3 = *(const frag8*)&As[s][(rowA0 + 48) * 32 + rk];
        if (kt + 3 < NT) STAGE_A(kt + 3);
        __builtin_amdgcn_s_barrier();
        asm volatile("" ::: "memory");
        __builtin_amdgcn_s_setprio(1);
        acc[0][0] = __builtin_amdgcn_mfma_f32_16x16x32_bf16(fa0, fb0, acc[0][0], 0, 0, 0);
        acc[0][1] = __builtin_amdgcn_mfma_f32_16x16x32_bf16(fa0, fb1, acc[0][1], 0, 0, 0);
        acc[0][2] = __builtin_amdgcn_mfma_f32_16x16x32_bf16(fa0, fb2, acc[0][2], 0, 0, 0);
        acc[0][3] = __builtin_amdgcn_mfma_f32_16x16x32_bf16(fa0, fb3, acc[0][3], 0, 0, 0);
        acc[1][0] = __builtin_amdgcn_mfma_f32_16x16x32_bf16(fa1, fb0, acc[1][0], 0, 0, 0);
        acc[1][1] = __builtin_amdgcn_mfma_f32_16x16x32_bf16(fa1, fb1, acc[1][1], 0, 0, 0);
        acc[1][2] = __builtin_amdgcn_mfma_f32_16x16x32_bf16(fa1, fb2, acc[1][2], 0, 0, 0);
        acc[1][3] = __builtin_amdgcn_mfma_f32_16x16x32_bf16(fa1, fb3, acc[1][3], 0, 0, 0);
        acc[2][0] = __builtin_amdgcn_mfma_f32_16x16x32_bf16(fa2, fb0, acc[2][0], 0, 0, 0);
        acc[2][1] = __builtin_amdgcn_mfma_f32_16x16x32_bf16(fa2, fb1, acc[2][1], 0, 0, 0);
        acc[2][2] = __builtin_amdgcn_mfma_f32_16x16x32_bf16(fa2, fb2, acc[2][2], 0, 0, 0);
        acc[2][3] = __builtin_amdgcn_mfma_f32_16x16x32_bf16(fa2, fb3, acc[2][3], 0, 0, 0);
        acc[3][0] = __builtin_amdgcn_mfma_f32_16x16x32_bf16(fa3, fb0, acc[3][0], 0, 0, 0);
        acc[3][1] = __builtin_amdgcn_mfma_f32_16x16x32_bf16(fa3, fb1, acc[3][1], 0, 0, 0);
        acc[3][2] = __builtin_amdgcn_mfma_f32_16x16x32_bf16(fa3, fb2, acc[3][2], 0, 0, 0);
        acc[3][3] = __builtin_amdgcn_mfma_f32_16x16x32_bf16(fa3, fb3, acc[3][3], 0, 0, 0);
        __builtin_amdgcn_s_setprio(0);
        asm volatile("" ::: "memory");
        __builtin_amdgcn_s_barrier();
        asm volatile("" ::: "memory");
        // ---- phase B: ds_read A(4..7); stage B-part of kt+3 ----
        frag8 fa4 = *(const frag8*)&As[s][(rowA0 +  64) * 32 + rk];
        frag8 fa5 = *(const frag8*)&As[s][(rowA0 +  80) * 32 + rk];
        frag8 fa6 = *(const frag8*)&As[s][(rowA0 +  96) * 32 + rk];
        frag8 fa7 = *(const frag8*)&As[s][(rowA0 + 112) * 32 + rk];
        if (kt + 3 < NT) STAGE_B(kt + 3);
        __builtin_amdgcn_s_barrier();
        asm volatile("" ::: "memory");
        __builtin_amdgcn_s_setprio(1);
        acc[4][0] = __builtin_amdgcn_mfma_f32_16x16x32_bf16(fa4, fb0, acc[4][0], 0, 0, 0);
        acc[4][1] = __builtin_amdgcn_mfma_f32_16x16x32_bf16(fa4, fb1, acc[4][1], 0, 0, 0);
        acc[4][2] = __builtin_amdgcn_mfma_f32_16x16x32_bf16(fa4, fb2, acc[4][2], 0, 0, 0);
        acc[4][3] = __builtin_amdgcn_mfma_f32_16x16x32_bf16(fa4, fb3, acc[4][3], 0, 0, 0);
        acc[5][0] = __builtin_amdgcn_mfma_f32_16x16x32_bf16(fa5, fb0, acc[5][0], 0, 0, 0);
        acc[5][1] = __builtin_amdgcn_mfma_f32_16x16x32_bf16(fa5, fb1, acc[5][1], 0, 0, 0);
        acc[5][2] = __builtin_amdgcn_mfma_f32_16x16x32_bf16(fa5, fb2, acc[5][2], 0, 0, 0);
        acc[5][3] = __builtin_amdgcn_mfma_f32_16x16x32_bf16(fa5, fb3, acc[5][3], 0, 0, 0);
        acc[6][0] = __builtin_amdgcn_mfma_f32_16x16x32_bf16(fa6, fb0, acc[6][0], 0, 0, 0);
        acc[6][1] = __builtin_amdgcn_mfma_f32_16x16x32_bf16(fa6, fb1, acc[6][1], 0, 0, 0);
        acc[6][2] = __builtin_amdgcn_mfma_f32_16x16x32_bf16(fa6, fb2, acc[6][2], 0, 0, 0);
        acc[6][3] = __builtin_amdgcn_mfma_f32_16x16x32_bf16(fa6, fb3, acc[6][3], 0, 0, 0);
        acc[7][0] = __builtin_amdgcn_mfma_f32_16x16x32_bf16(fa7, fb0, acc[7][0], 0, 0, 0);
        acc[7][1] = __builtin_amdgcn_mfma_f32_16x16x32_bf16(fa7, fb1, acc[7][1], 0, 0, 0);
        acc[7][2] = __builtin_amdgcn_mfma_f32_16x16x32_bf16(fa7, fb2, acc[7][2], 0, 0, 0);
        acc[7][3] = __builtin_amdgcn_mfma_f32_16x16x32_bf16(fa7, fb3, acc[7][3], 0, 0, 0);
        __builtin_amdgcn_s_setprio(0);
        asm volatile("" ::: "memory");
        // tile boundary: tile kt+1 must be landed for ALL waves after this barrier
        if (kt < NT - 3)       { asm volatile("s_waitcnt vmcnt(8)" ::: "memory"); }
        else if (kt == NT - 3) { asm volatile("s_waitcnt vmcnt(4)" ::: "memory"); }
        else if (kt == NT - 2) { asm volatile("s_waitcnt vmcnt(0)" ::: "memory"); }
        __builtin_amdgcn_s_barrier();
        asm volatile("" ::: "memory");
    }
#undef STAGE_A
#undef STAGE_B

    // epilogue: C/D layout col=lane&15, row=(lane>>4)*4+j  [m89-verified]
    const int r4 = (l >> 4) * 4;
    const int cl = l & 15;
#pragma unroll
    for (int fm = 0; fm < 8; ++fm) {
#pragma unroll
        for (int fn = 0; fn < 4; ++fn) {
            const int n = bn * 256 + wc * 64 + fn * 16 + cl;
            const float bn_bias = bias[n];
#pragma unroll
            for (int j = 0; j < 4; ++j) {
                const int m = bm * 256 + wr * 128 + fm * 16 + r4 + j;
                float v = acc[fm][fn][j] + bn_bias;
                if (EPI == 1) {
                    if (n < 1024) {
                        out0[(long)m * 1024 + n] = 1.0f / (1.0f + expf(-v));
                    } else {
                        bf16 h = __float2bfloat16(v);
                        float lof = v - __bfloat162float(h);
                        const int d = n - 1024;
                        outv[(long)m * KP + d]        = h;
                        outv[(long)m * KP + d + 1024] = __float2bfloat16(lof);
                    }
                } else if (EPI == 2) {
                    const float sv = tanhf(v);
                    const float g  = gatef_in[(long)m * 1024 + n];
                    out0[(long)m * 1024 + n] = 1.0f - g;
                    out1[(long)m * 1024 + n] = g * sv;
                } else {
                    out0[(long)m * 1024 + n] = x_in[(long)m * 1024 + n] + v;
                }
            }
        }
    }
}

// ---------------- chunked parallel scan: h[t] = a[t]*h[t-1] + b[t] ----------------
__global__ void scan_phase1(const float* __restrict__ af, const float* __restrict__ bfv,
                            float* __restrict__ Ach, float* __restrict__ Bch) {
    int tid = blockIdx.x * 256 + threadIdx.x;   // [chunk][b][d]
    int c = tid >> 12;
    int r = tid & 4095;
    int bi = r >> 10;
    long base = ((long)bi * T_DIM + c * CHL) * D_DIM + (r & 1023);
    float A = 1.0f, Bc = 0.0f;
#pragma unroll 4
    for (int i = 0; i < CHL; ++i) {
        float a = af[base + (long)i * D_DIM];
        float b = bfv[base + (long)i * D_DIM];
        A *= a;
        Bc = a * Bc + b;
    }
    Ach[tid] = A;
    Bch[tid] = Bc;
}

__global__ void scan_phase2(const float* __restrict__ Ach, const float* __restrict__ Bch,
                            float* __restrict__ carry) {
    int r = blockIdx.x * 256 + threadIdx.x;   // 0..4095
    float h = 0.0f;
#pragma unroll
    for (int c = 0; c < NCH; ++c) {
        carry[c * 4096 + r] = h;
        h = Ach[c * 4096 + r] * h + Bch[c * 4096 + r];
    }
}

__global__ void scan_phase3(const float* __restrict__ af, const float* __restrict__ bfv,
                            const float* __restrict__ carry, bf16* __restrict__ Hs) {
    int tid = blockIdx.x * 256 + threadIdx.x;
    int c = tid >> 12;
    int r = tid & 4095;
    int bi = r >> 10;
    int d  = r & 1023;
    long base = ((long)bi * T_DIM + c * CHL) * D_DIM + d;
    float h = carry[tid];
#pragma unroll 4
    for (int i = 0; i < CHL; ++i) {
        float a = af[base + (long)i * D_DIM];
        float b = bfv[base + (long)i * D_DIM];
        h = a * h + b;
        long m = (long)bi * T_DIM + c * CHL + i;
        bf16 hh = __float2bfloat16(h);
        float lof = h - __bfloat162float(hh);
        Hs[m * KP + d]        = hh;
        Hs[m * KP + d + 1024] = __float2bfloat16(lof);
    }
}

// ---------------- launch ----------------
extern "C" void kernel_launch(void* const* d_in, const int* in_sizes, int n_in,
                              void* d_out, int out_size, void* d_ws, size_t ws_size,
                              hipStream_t stream) {
    const float* x   = (const float*)d_in[0];
    const float* Win = (const float*)d_in[1];
    const float* bin = (const float*)d_in[2];
    const float* Wsm = (const float*)d_in[3];
    const float* bs  = (const float*)d_in[4];
    const float* Wo  = (const float*)d_in[5];
    const float* bo  = (const float*)d_in[6];
    float* out = (float*)d_out;
    char*  ws  = (char*)d_ws;

    bf16*  Xs    = (bf16*)(ws + XS_OFF);   // also Hs after GEMM1 consumes Xs
    bf16*  Wins  = (bf16*)(ws + WIN_OFF);
    bf16*  Wss   = (bf16*)(ws + WSS_OFF);
    bf16*  Wos   = (bf16*)(ws + WOS_OFF);
    float* gatef = (float*)(ws + GATE_OFF);
    bf16*  Vs    = (bf16*)(ws + VS_OFF);
    float* af    = (float*)(ws + AF_OFF);
    float* bfv   = (float*)(ws + BF_OFF);
    float* Ach   = (float*)(ws + ACH_OFF);
    float* Bch   = (float*)(ws + BCH_OFF);
    float* car   = (float*)(ws + CAR_OFF);

    // activation split (hi|lo) and weight converts (hi only)
    split_kernel   <<<(M_DIM * D_DIM / 4 + 255) / 256, 256, 0, stream>>>(x,   Xs,   (long)M_DIM * D_DIM / 4);
    split_hi_kernel<<<(2048 * 1024 / 4 + 255) / 256,  256, 0, stream>>>(Win, Wins, 2048L * 1024 / 4);
    split_hi_kernel<<<(1024 * 1024 / 4 + 255) / 256,  256, 0, stream>>>(Wsm, Wss,  1024L * 1024 / 4);
    split_hi_kernel<<<(1024 * 1024 / 4 + 255) / 256,  256, 0, stream>>>(Wo,  Wos,  1024L * 1024 / 4);

    // GEMM1: gv = x @ W_in^T ; gate/val epilogue
    dim3 g1(M_DIM / 256, 2048 / 256);
    gemm8p<1><<<g1, 512, 0, stream>>>(Xs, Wins, bin, nullptr, nullptr, gatef, nullptr, Vs);

    // GEMM2: sv = tanh(val @ W_s^T) ; a,b epilogue
    dim3 g2(M_DIM / 256, 1024 / 256);
    gemm8p<2><<<g2, 512, 0, stream>>>(Vs, Wss, bs, gatef, nullptr, af, bfv, nullptr);

    // scan: h[t] = a[t]*h[t-1] + b[t]
    scan_phase1<<<NCH * 4096 / 256, 256, 0, stream>>>(af, bfv, Ach, Bch);
    scan_phase2<<<4096 / 256, 256, 0, stream>>>(Ach, Bch, car);
    scan_phase3<<<NCH * 4096 / 256, 256, 0, stream>>>(af, bfv, car, Xs /*Hs*/);

    // GEMM3: out = x + h @ W_o^T + b_o
    gemm8p<3><<<g2, 512, 0, stream>>>(Xs, Wos, bo, nullptr, x, out, nullptr, nullptr);
}

// Round 8
// 311.415 us; speedup vs baseline: 1.3638x; 1.3638x over previous
//
#include <hip/hip_runtime.h>
#include <hip/hip_bf16.h>
#include <cmath>

// Problem constants
#define B_DIM 4
#define T_DIM 2048
#define D_DIM 1024
#define M_DIM 8192          // B*T
#define KP    2048          // physical K for GEMM1 activations: [hi|lo]

#define NCH   64            // scan chunks
#define CHL   32            // T / NCH

using bf16 = __hip_bfloat16;
typedef __attribute__((ext_vector_type(8))) short frag8;   // 8 bf16 (4 VGPRs)
typedef __attribute__((ext_vector_type(4))) float f32x4;   // MFMA accumulator

// ---------------- workspace layout (bytes) ----------------
// Xs   (8192x2048 bf16 hi|lo; first 16MB aliased by Hs)   33,554,432
// Wins (2048x1024 bf16)                                    4,194,304
// Wss  (1024x1024 bf16)                                    2,097,152
// Wos  (1024x1024 bf16)                                    2,097,152
// gatef(8192x1024 f32)                                    33,554,432
// Vs   (8192x1024 bf16, hi only)                          16,777,216
// af   (8192x1024 f32)                                    33,554,432
// bf   (8192x1024 f32)                                    33,554,432
// Ach/Bch/carry (64*4096 f32 each)                         3,145,728
#define XS_OFF   0L
#define WIN_OFF  33554432L
#define WSS_OFF  37748736L
#define WOS_OFF  39845888L
#define GATE_OFF 41943040L
#define VS_OFF   75497472L
#define AF_OFF   92274688L
#define BF_OFF   125829120L
#define ACH_OFF  159383552L
#define BCH_OFF  160432128L
#define CAR_OFF  161480704L

// ---------------- hi/lo split convert for GEMM1 activations (4 f32/thread) ----------------
__global__ void split_kernel(const float* __restrict__ src, bf16* __restrict__ dst, long total4) {
    long i4 = (long)blockIdx.x * blockDim.x + threadIdx.x;
    if (i4 >= total4) return;
    long i = i4 * 4;
    const float4 v = *(const float4*)&src[i];
    long r = i >> 10;
    int  c = (int)(i & 1023);
    ushort hi[4], lo[4];
    const float vv[4] = {v.x, v.y, v.z, v.w};
#pragma unroll
    for (int j = 0; j < 4; ++j) {
        bf16 h = __float2bfloat16(vv[j]);
        hi[j] = *(ushort*)&h;
        bf16 l2 = __float2bfloat16(vv[j] - __bfloat162float(h));
        lo[j] = *(ushort*)&l2;
    }
    *(ushort4*)&dst[r * KP + c]        = make_ushort4(hi[0], hi[1], hi[2], hi[3]);
    *(ushort4*)&dst[r * KP + c + 1024] = make_ushort4(lo[0], lo[1], lo[2], lo[3]);
}

// weights: plain RN-bf16 convert, [N][1024]
__global__ void split_hi_kernel(const float* __restrict__ src, bf16* __restrict__ dst, long total4) {
    long i4 = (long)blockIdx.x * blockDim.x + threadIdx.x;
    if (i4 >= total4) return;
    long i = i4 * 4;
    const float4 v = *(const float4*)&src[i];
    bf16 h0 = __float2bfloat16(v.x), h1 = __float2bfloat16(v.y);
    bf16 h2 = __float2bfloat16(v.z), h3 = __float2bfloat16(v.w);
    *(ushort4*)&dst[i] = make_ushort4(*(ushort*)&h0, *(ushort*)&h1, *(ushort*)&h2, *(ushort*)&h3);
}

// ---------------- 128x128 / BK=32 / 4-wave / ring-4 counted-vmcnt GEMM ----------------
// C[m,n] = sum_{kt<NTT} A[m, kt*32+..] * Bhi[n, (kt&31)*32+..]
//   GEMM1: NTT=64, LDA=2048 -> (hi_a + lo_a) . hi_b over K'=2048
//   GEMM2/3: NTT=32, LDA=1024 -> plain bf16 K'=1024
// LDS: ring-4 per operand, slot = 128x32 bf16 (8 KiB) -> 64 KiB total -> 2 blocks/CU.
// Swizzle (T2, involution): LDS(row, chunk q) holds global chunk q ^ g(row),
//   g(r) = (r&3)^((r>>2)&3); applied as pre-swizzled GLOBAL source col
//   (linear global_load_lds dest, rule #21) + swizzled ds_read chunk.
// Per K-tile kt (slot kt&3): {8 ds_read; STAGE(kt+3)=4 loads; setprio(1); 16 MFMA;
//   setprio(0); vmcnt-ladder; barrier}. vmcnt(8) = tiles kt+2,kt+3 stay in flight
//   (never 0 in steady state); barrier globalizes tile kt+1's landing.
// Single trailing barrier/tile is hazard-safe: slot kt+3 == slot kt-1; its readers'
//   lgkm-drains complete before the previous trailing barrier; DMA issues after it.
#define AS1 const __attribute__((address_space(1))) void*
#define AS3 __attribute__((address_space(3))) void*

template<int EPI, int NTT, int LDA>
__global__ __launch_bounds__(256, 2)
void gemm128(const bf16* __restrict__ A, const bf16* __restrict__ Bw,
             const float* __restrict__ bias,
             const float* __restrict__ gatef_in,
             const float* __restrict__ x_in,
             float* __restrict__ out0, float* __restrict__ out1,
             bf16* __restrict__ outv)
{
    __shared__ bf16 As[4][4096];   // [slot][128*32]
    __shared__ bf16 Bs[4][4096];
    const int t  = threadIdx.x;
    const int l  = t & 63;
    const int w  = t >> 6;
    const int wr = w >> 1, wc = w & 1;
    const int bm = blockIdx.x;
    const int bn = blockIdx.y;

    f32x4 acc[4][4] = {};

    // staging: thread t -> rows sr, sr+64; col chunk (t&3), source col pre-swizzled
    const int sr  = t >> 2;                           // 0..63
    const int sg  = (sr & 3) ^ ((sr >> 2) & 3);       // same for sr+64
    const int scS = ((t & 3) * 8) ^ (sg << 3);
    const bf16* Ab = A  + ((long)bm * 128 + sr) * LDA  + scS;
    const bf16* Bb = Bw + ((long)bn * 128 + sr) * 1024 + scS;

    // reader: swizzled k-chunk; g(row) = (l&3)^((l>>2)&3) for all frag rows
    const int rk    = (((l >> 4) ^ (l & 3) ^ ((l >> 2) & 3)) << 3);
    const int rowA0 = wr * 64 + (l & 15);
    const int rowB0 = wc * 64 + (l & 15);

#define STAGE(kt) {                                                                \
    const int  s_ = (kt) & 3;                                                      \
    const long ka = (long)(kt) * 32;                                               \
    const long kb = (long)((kt) & 31) * 32;                                        \
    __builtin_amdgcn_global_load_lds((AS1)(Ab + ka),             (AS3)&As[s_][t * 8],        16, 0, 0); \
    __builtin_amdgcn_global_load_lds((AS1)(Ab + 64 * LDA + ka),  (AS3)&As[s_][2048 + t * 8], 16, 0, 0); \
    __builtin_amdgcn_global_load_lds((AS1)(Bb + kb),             (AS3)&Bs[s_][t * 8],        16, 0, 0); \
    __builtin_amdgcn_global_load_lds((AS1)(Bb + 64 * 1024 + kb), (AS3)&Bs[s_][2048 + t * 8], 16, 0, 0); \
}

    // prologue: tiles 0,1,2 in flight (12 loads/thread)
    STAGE(0); STAGE(1); STAGE(2);
    asm volatile("s_waitcnt vmcnt(8)" ::: "memory");   // tile 0 landed (this wave)
    __builtin_amdgcn_s_barrier();                      // ...landed for ALL waves
    asm volatile("" ::: "memory");

    for (int kt = 0; kt < NTT; ++kt) {
        const int s = kt & 3;
        frag8 fb0 = *(const frag8*)&Bs[s][(rowB0     ) * 32 + rk];
        frag8 fb1 = *(const frag8*)&Bs[s][(rowB0 + 16) * 32 + rk];
        frag8 fb2 = *(const frag8*)&Bs[s][(rowB0 + 32) * 32 + rk];
        frag8 fb3 = *(const frag8*)&Bs[s][(rowB0 + 48) * 32 + rk];
        frag8 fa0 = *(const frag8*)&As[s][(rowA0     ) * 32 + rk];
        frag8 fa1 = *(const frag8*)&As[s][(rowA0 + 16) * 32 + rk];
        frag8 fa2 = *(const frag8*)&As[s][(rowA0 + 32) * 32 + rk];
        frag8 fa3 = *(const frag8*)&As[s][(rowA0 + 48) * 32 + rk];
        if (kt + 3 < NTT) STAGE(kt + 3);
        __builtin_amdgcn_s_setprio(1);
        acc[0][0] = __builtin_amdgcn_mfma_f32_16x16x32_bf16(fa0, fb0, acc[0][0], 0, 0, 0);
        acc[0][1] = __builtin_amdgcn_mfma_f32_16x16x32_bf16(fa0, fb1, acc[0][1], 0, 0, 0);
        acc[0][2] = __builtin_amdgcn_mfma_f32_16x16x32_bf16(fa0, fb2, acc[0][2], 0, 0, 0);
        acc[0][3] = __builtin_amdgcn_mfma_f32_16x16x32_bf16(fa0, fb3, acc[0][3], 0, 0, 0);
        acc[1][0] = __builtin_amdgcn_mfma_f32_16x16x32_bf16(fa1, fb0, acc[1][0], 0, 0, 0);
        acc[1][1] = __builtin_amdgcn_mfma_f32_16x16x32_bf16(fa1, fb1, acc[1][1], 0, 0, 0);
        acc[1][2] = __builtin_amdgcn_mfma_f32_16x16x32_bf16(fa1, fb2, acc[1][2], 0, 0, 0);
        acc[1][3] = __builtin_amdgcn_mfma_f32_16x16x32_bf16(fa1, fb3, acc[1][3], 0, 0, 0);
        acc[2][0] = __builtin_amdgcn_mfma_f32_16x16x32_bf16(fa2, fb0, acc[2][0], 0, 0, 0);
        acc[2][1] = __builtin_amdgcn_mfma_f32_16x16x32_bf16(fa2, fb1, acc[2][1], 0, 0, 0);
        acc[2][2] = __builtin_amdgcn_mfma_f32_16x16x32_bf16(fa2, fb2, acc[2][2], 0, 0, 0);
        acc[2][3] = __builtin_amdgcn_mfma_f32_16x16x32_bf16(fa2, fb3, acc[2][3], 0, 0, 0);
        acc[3][0] = __builtin_amdgcn_mfma_f32_16x16x32_bf16(fa3, fb0, acc[3][0], 0, 0, 0);
        acc[3][1] = __builtin_amdgcn_mfma_f32_16x16x32_bf16(fa3, fb1, acc[3][1], 0, 0, 0);
        acc[3][2] = __builtin_amdgcn_mfma_f32_16x16x32_bf16(fa3, fb2, acc[3][2], 0, 0, 0);
        acc[3][3] = __builtin_amdgcn_mfma_f32_16x16x32_bf16(fa3, fb3, acc[3][3], 0, 0, 0);
        __builtin_amdgcn_s_setprio(0);
        asm volatile("" ::: "memory");
        // tile kt+1 must be landed for ALL waves after this barrier
        if (kt < NTT - 3)       { asm volatile("s_waitcnt vmcnt(8)" ::: "memory"); }
        else if (kt == NTT - 3) { asm volatile("s_waitcnt vmcnt(4)" ::: "memory"); }
        else if (kt == NTT - 2) { asm volatile("s_waitcnt vmcnt(0)" ::: "memory"); }
        __builtin_amdgcn_s_barrier();
        asm volatile("" ::: "memory");
    }
#undef STAGE

    // epilogue: C/D layout col=lane&15, row=(lane>>4)*4+j  [m89-verified]
    const int r4 = (l >> 4) * 4;
    const int cl = l & 15;
#pragma unroll
    for (int fm = 0; fm < 4; ++fm) {
#pragma unroll
        for (int fn = 0; fn < 4; ++fn) {
            const int n = bn * 128 + wc * 64 + fn * 16 + cl;
            const float bn_bias = bias[n];
#pragma unroll
            for (int j = 0; j < 4; ++j) {
                const int m = bm * 128 + wr * 64 + fm * 16 + r4 + j;
                float v = acc[fm][fn][j] + bn_bias;
                if (EPI == 1) {
                    if (n < 1024) {
                        out0[(long)m * 1024 + n] = 1.0f / (1.0f + expf(-v));
                    } else {
                        outv[(long)m * 1024 + (n - 1024)] = __float2bfloat16(v);
                    }
                } else if (EPI == 2) {
                    const float sv = tanhf(v);
                    const float g  = gatef_in[(long)m * 1024 + n];
                    out0[(long)m * 1024 + n] = 1.0f - g;
                    out1[(long)m * 1024 + n] = g * sv;
                } else {
                    out0[(long)m * 1024 + n] = x_in[(long)m * 1024 + n] + v;
                }
            }
        }
    }
}

// ---------------- chunked parallel scan: h[t] = a[t]*h[t-1] + b[t] ----------------
__global__ void scan_phase1(const float* __restrict__ af, const float* __restrict__ bfv,
                            float* __restrict__ Ach, float* __restrict__ Bch) {
    int tid = blockIdx.x * 256 + threadIdx.x;   // [chunk][b][d]
    int c = tid >> 12;
    int r = tid & 4095;
    int bi = r >> 10;
    long base = ((long)bi * T_DIM + c * CHL) * D_DIM + (r & 1023);
    float A = 1.0f, Bc = 0.0f;
#pragma unroll 4
    for (int i = 0; i < CHL; ++i) {
        float a = af[base + (long)i * D_DIM];
        float b = bfv[base + (long)i * D_DIM];
        A *= a;
        Bc = a * Bc + b;
    }
    Ach[tid] = A;
    Bch[tid] = Bc;
}

__global__ void scan_phase2(const float* __restrict__ Ach, const float* __restrict__ Bch,
                            float* __restrict__ carry) {
    int r = blockIdx.x * 256 + threadIdx.x;   // 0..4095
    float h = 0.0f;
#pragma unroll
    for (int c = 0; c < NCH; ++c) {
        carry[c * 4096 + r] = h;
        h = Ach[c * 4096 + r] * h + Bch[c * 4096 + r];
    }
}

__global__ void scan_phase3(const float* __restrict__ af, const float* __restrict__ bfv,
                            const float* __restrict__ carry, bf16* __restrict__ Hs) {
    int tid = blockIdx.x * 256 + threadIdx.x;
    int c = tid >> 12;
    int r = tid & 4095;
    int bi = r >> 10;
    int d  = r & 1023;
    long base = ((long)bi * T_DIM + c * CHL) * D_DIM + d;
    float h = carry[tid];
#pragma unroll 4
    for (int i = 0; i < CHL; ++i) {
        float a = af[base + (long)i * D_DIM];
        float b = bfv[base + (long)i * D_DIM];
        h = a * h + b;
        long m = (long)bi * T_DIM + c * CHL + i;
        Hs[m * 1024 + d] = __float2bfloat16(h);
    }
}

// ---------------- launch ----------------
extern "C" void kernel_launch(void* const* d_in, const int* in_sizes, int n_in,
                              void* d_out, int out_size, void* d_ws, size_t ws_size,
                              hipStream_t stream) {
    const float* x   = (const float*)d_in[0];
    const float* Win = (const float*)d_in[1];
    const float* bin = (const float*)d_in[2];
    const float* Wsm = (const float*)d_in[3];
    const float* bs  = (const float*)d_in[4];
    const float* Wo  = (const float*)d_in[5];
    const float* bo  = (const float*)d_in[6];
    float* out = (float*)d_out;
    char*  ws  = (char*)d_ws;

    bf16*  Xs    = (bf16*)(ws + XS_OFF);   // [M][2048] hi|lo; first 16MB reused as Hs
    bf16*  Wins  = (bf16*)(ws + WIN_OFF);
    bf16*  Wss   = (bf16*)(ws + WSS_OFF);
    bf16*  Wos   = (bf16*)(ws + WOS_OFF);
    float* gatef = (float*)(ws + GATE_OFF);
    bf16*  Vs    = (bf16*)(ws + VS_OFF);   // [M][1024] hi only
    float* af    = (float*)(ws + AF_OFF);
    float* bfv   = (float*)(ws + BF_OFF);
    float* Ach   = (float*)(ws + ACH_OFF);
    float* Bch   = (float*)(ws + BCH_OFF);
    float* car   = (float*)(ws + CAR_OFF);
    bf16*  Hs    = (bf16*)(ws + XS_OFF);   // [M][1024] hi only (aliases Xs)

    // activation split (hi|lo) and weight converts (hi only)
    split_kernel   <<<(M_DIM * D_DIM / 4 + 255) / 256, 256, 0, stream>>>(x,   Xs,   (long)M_DIM * D_DIM / 4);
    split_hi_kernel<<<(2048 * 1024 / 4 + 255) / 256,  256, 0, stream>>>(Win, Wins, 2048L * 1024 / 4);
    split_hi_kernel<<<(1024 * 1024 / 4 + 255) / 256,  256, 0, stream>>>(Wsm, Wss,  1024L * 1024 / 4);
    split_hi_kernel<<<(1024 * 1024 / 4 + 255) / 256,  256, 0, stream>>>(Wo,  Wos,  1024L * 1024 / 4);

    // GEMM1: gv = x @ W_in^T ; gate/val epilogue (K'=2048: hi+lo activations)
    dim3 g1(M_DIM / 128, 2048 / 128);
    gemm128<1, 64, 2048><<<g1, 256, 0, stream>>>(Xs, Wins, bin, nullptr, nullptr, gatef, nullptr, Vs);

    // GEMM2: sv = tanh(val @ W_s^T) ; a,b epilogue (K'=1024: bf16 val)
    dim3 g2(M_DIM / 128, 1024 / 128);
    gemm128<2, 32, 1024><<<g2, 256, 0, stream>>>(Vs, Wss, bs, gatef, nullptr, af, bfv, nullptr);

    // scan: h[t] = a[t]*h[t-1] + b[t]
    scan_phase1<<<NCH * 4096 / 256, 256, 0, stream>>>(af, bfv, Ach, Bch);
    scan_phase2<<<4096 / 256, 256, 0, stream>>>(Ach, Bch, car);
    scan_phase3<<<NCH * 4096 / 256, 256, 0, stream>>>(af, bfv, car, Hs);

    // GEMM3: out = x + h @ W_o^T + b_o (K'=1024: bf16 h)
    gemm128<3, 32, 1024><<<g2, 256, 0, stream>>>(Hs, Wos, bo, nullptr, x, out, nullptr, nullptr);
}

// Round 9
// 302.227 us; speedup vs baseline: 1.4053x; 1.0304x over previous
//
#include <hip/hip_runtime.h>
#include <hip/hip_bf16.h>
#include <cmath>

// Problem constants
#define B_DIM 4
#define T_DIM 2048
#define D_DIM 1024
#define M_DIM 8192          // B*T
#define KP    2048          // physical K for GEMM1 activations: [hi|lo]

#define NCH   64            // scan chunks
#define CHL   32            // T / NCH

using bf16 = __hip_bfloat16;
typedef __attribute__((ext_vector_type(8))) short frag8;   // 8 bf16 (4 VGPRs)
typedef __attribute__((ext_vector_type(4))) float f32x4;   // MFMA accumulator

// ---------------- workspace layout (bytes) ----------------
#define XS_OFF   0L
#define WIN_OFF  33554432L
#define WSS_OFF  37748736L
#define WOS_OFF  39845888L
#define GATE_OFF 41943040L
#define VS_OFF   75497472L
#define AF_OFF   92274688L
#define BF_OFF   125829120L
#define ACH_OFF  159383552L
#define BCH_OFF  160432128L

// ---------------- hi/lo split convert for GEMM1 activations (4 f32/thread) ----------------
__global__ void split_kernel(const float* __restrict__ src, bf16* __restrict__ dst, long total4) {
    long i4 = (long)blockIdx.x * blockDim.x + threadIdx.x;
    if (i4 >= total4) return;
    long i = i4 * 4;
    const float4 v = *(const float4*)&src[i];
    long r = i >> 10;
    int  c = (int)(i & 1023);
    ushort hi[4], lo[4];
    const float vv[4] = {v.x, v.y, v.z, v.w};
#pragma unroll
    for (int j = 0; j < 4; ++j) {
        bf16 h = __float2bfloat16(vv[j]);
        hi[j] = *(ushort*)&h;
        bf16 l2 = __float2bfloat16(vv[j] - __bfloat162float(h));
        lo[j] = *(ushort*)&l2;
    }
    *(ushort4*)&dst[r * KP + c]        = make_ushort4(hi[0], hi[1], hi[2], hi[3]);
    *(ushort4*)&dst[r * KP + c + 1024] = make_ushort4(lo[0], lo[1], lo[2], lo[3]);
}

// merged weight converts: Win(2M) | Wsm(1M) | Wo(1M) f32 -> bf16, one dispatch.
// Range boundaries are multiples of 256 i4-groups -> branch is block-uniform.
__global__ void wconv_kernel(const float* __restrict__ Win, const float* __restrict__ Wsm,
                             const float* __restrict__ Wo,
                             bf16* __restrict__ Wins, bf16* __restrict__ Wss,
                             bf16* __restrict__ Wos) {
    long i4 = (long)blockIdx.x * 256 + threadIdx.x;   // 0..1048575
    const float* src; bf16* dst; long off;
    if (i4 < 524288)      { src = Win; dst = Wins; off = i4; }
    else if (i4 < 786432) { src = Wsm; dst = Wss;  off = i4 - 524288; }
    else                  { src = Wo;  dst = Wos;  off = i4 - 786432; }
    long i = off * 4;
    const float4 v = *(const float4*)&src[i];
    bf16 h0 = __float2bfloat16(v.x), h1 = __float2bfloat16(v.y);
    bf16 h2 = __float2bfloat16(v.z), h3 = __float2bfloat16(v.w);
    *(ushort4*)&dst[i] = make_ushort4(*(ushort*)&h0, *(ushort*)&h1, *(ushort*)&h2, *(ushort*)&h3);
}

// ---------------- 128x128 / BK=32 / 4-wave / ring-3 counted-vmcnt GEMM ----------------
// C[m,n] = sum_{kt<NTT} A[m, kt*32+..] * Bhi[n, (kt&31)*32+..]
//   GEMM1: NTT=64, LDA=2048 -> (hi_a + lo_a) . hi_b over K'=2048
//   GEMM2/3: NTT=32, LDA=1024 -> plain bf16 K'=1024
// LDS: ring-3 per operand, slot = 128x32 bf16 (8 KiB) -> 48 KiB total -> 3 blocks/CU.
// Swizzle (T2, involution, R8-validated): LDS(row, chunk q) holds global chunk
//   q ^ g(row), g(r) = (r&3)^((r>>2)&3); pre-swizzled GLOBAL source col
//   (linear global_load_lds dest, rule #21) + swizzled ds_read chunk.
// Per K-tile kt (read slot kt%3): {8 ds_read; STAGE(kt+2) into slot (kt+2)%3;
//   setprio(1); 16 MFMA; setprio(0); vmcnt-ladder; barrier}.
// Steady-state ladder: outstanding at wait = tiles kt+1,kt+2 (8 loads) -> vmcnt(4)
//   waits tile kt+1 only (never 0 until tail). Barrier globalizes its landing.
// Slot hazard: stage slot (kt+2)%3 == (kt-1)%3; tile kt-1's ds_reads drained
//   (lgkm) before its trailing barrier, which precedes this stage. Safe.
#define AS1 const __attribute__((address_space(1))) void*
#define AS3 __attribute__((address_space(3))) void*

template<int EPI, int NTT, int LDA>
__global__ __launch_bounds__(256, 3)
void gemm128(const bf16* __restrict__ A, const bf16* __restrict__ Bw,
             const float* __restrict__ bias,
             const float* __restrict__ gatef_in,
             const float* __restrict__ x_in,
             float* __restrict__ out0, float* __restrict__ out1,
             bf16* __restrict__ outv)
{
    __shared__ bf16 As[3][4096];   // [slot][128*32]
    __shared__ bf16 Bs[3][4096];
    const int t  = threadIdx.x;
    const int l  = t & 63;
    const int w  = t >> 6;
    const int wr = w >> 1, wc = w & 1;
    const int bm = blockIdx.x;
    const int bn = blockIdx.y;

    f32x4 acc[4][4] = {};

    // staging: thread t -> rows sr, sr+64; col chunk (t&3), source col pre-swizzled
    const int sr  = t >> 2;                           // 0..63
    const int sg  = (sr & 3) ^ ((sr >> 2) & 3);       // same for sr+64
    const int scS = ((t & 3) * 8) ^ (sg << 3);
    const bf16* Ab = A  + ((long)bm * 128 + sr) * LDA  + scS;
    const bf16* Bb = Bw + ((long)bn * 128 + sr) * 1024 + scS;

    // reader: swizzled k-chunk; g(row) = (l&3)^((l>>2)&3) for all frag rows
    const int rk    = (((l >> 4) ^ (l & 3) ^ ((l >> 2) & 3)) << 3);
    const int rowA0 = wr * 64 + (l & 15);
    const int rowB0 = wc * 64 + (l & 15);

#define STAGE(slot, kt) {                                                          \
    const long ka = (long)(kt) * 32;                                               \
    const long kb = (long)((kt) & 31) * 32;                                        \
    __builtin_amdgcn_global_load_lds((AS1)(Ab + ka),             (AS3)&As[slot][t * 8],        16, 0, 0); \
    __builtin_amdgcn_global_load_lds((AS1)(Ab + 64 * LDA + ka),  (AS3)&As[slot][2048 + t * 8], 16, 0, 0); \
    __builtin_amdgcn_global_load_lds((AS1)(Bb + kb),             (AS3)&Bs[slot][t * 8],        16, 0, 0); \
    __builtin_amdgcn_global_load_lds((AS1)(Bb + 64 * 1024 + kb), (AS3)&Bs[slot][2048 + t * 8], 16, 0, 0); \
}

    // prologue: tiles 0,1 in flight (8 loads/thread)
    STAGE(0, 0); STAGE(1, 1);
    asm volatile("s_waitcnt vmcnt(4)" ::: "memory");   // tile 0 landed (this wave)
    __builtin_amdgcn_s_barrier();                      // ...landed for ALL waves
    asm volatile("" ::: "memory");

    int sR = 0, sS = 2;   // read slot kt%3, stage slot (kt+2)%3
    for (int kt = 0; kt < NTT; ++kt) {
        frag8 fb0 = *(const frag8*)&Bs[sR][(rowB0     ) * 32 + rk];
        frag8 fb1 = *(const frag8*)&Bs[sR][(rowB0 + 16) * 32 + rk];
        frag8 fb2 = *(const frag8*)&Bs[sR][(rowB0 + 32) * 32 + rk];
        frag8 fb3 = *(const frag8*)&Bs[sR][(rowB0 + 48) * 32 + rk];
        frag8 fa0 = *(const frag8*)&As[sR][(rowA0     ) * 32 + rk];
        frag8 fa1 = *(const frag8*)&As[sR][(rowA0 + 16) * 32 + rk];
        frag8 fa2 = *(const frag8*)&As[sR][(rowA0 + 32) * 32 + rk];
        frag8 fa3 = *(const frag8*)&As[sR][(rowA0 + 48) * 32 + rk];
        if (kt + 2 < NTT) STAGE(sS, kt + 2);
        __builtin_amdgcn_s_setprio(1);
        acc[0][0] = __builtin_amdgcn_mfma_f32_16x16x32_bf16(fa0, fb0, acc[0][0], 0, 0, 0);
        acc[0][1] = __builtin_amdgcn_mfma_f32_16x16x32_bf16(fa0, fb1, acc[0][1], 0, 0, 0);
        acc[0][2] = __builtin_amdgcn_mfma_f32_16x16x32_bf16(fa0, fb2, acc[0][2], 0, 0, 0);
        acc[0][3] = __builtin_amdgcn_mfma_f32_16x16x32_bf16(fa0, fb3, acc[0][3], 0, 0, 0);
        acc[1][0] = __builtin_amdgcn_mfma_f32_16x16x32_bf16(fa1, fb0, acc[1][0], 0, 0, 0);
        acc[1][1] = __builtin_amdgcn_mfma_f32_16x16x32_bf16(fa1, fb1, acc[1][1], 0, 0, 0);
        acc[1][2] = __builtin_amdgcn_mfma_f32_16x16x32_bf16(fa1, fb2, acc[1][2], 0, 0, 0);
        acc[1][3] = __builtin_amdgcn_mfma_f32_16x16x32_bf16(fa1, fb3, acc[1][3], 0, 0, 0);
        acc[2][0] = __builtin_amdgcn_mfma_f32_16x16x32_bf16(fa2, fb0, acc[2][0], 0, 0, 0);
        acc[2][1] = __builtin_amdgcn_mfma_f32_16x16x32_bf16(fa2, fb1, acc[2][1], 0, 0, 0);
        acc[2][2] = __builtin_amdgcn_mfma_f32_16x16x32_bf16(fa2, fb2, acc[2][2], 0, 0, 0);
        acc[2][3] = __builtin_amdgcn_mfma_f32_16x16x32_bf16(fa2, fb3, acc[2][3], 0, 0, 0);
        acc[3][0] = __builtin_amdgcn_mfma_f32_16x16x32_bf16(fa3, fb0, acc[3][0], 0, 0, 0);
        acc[3][1] = __builtin_amdgcn_mfma_f32_16x16x32_bf16(fa3, fb1, acc[3][1], 0, 0, 0);
        acc[3][2] = __builtin_amdgcn_mfma_f32_16x16x32_bf16(fa3, fb2, acc[3][2], 0, 0, 0);
        acc[3][3] = __builtin_amdgcn_mfma_f32_16x16x32_bf16(fa3, fb3, acc[3][3], 0, 0, 0);
        __builtin_amdgcn_s_setprio(0);
        asm volatile("" ::: "memory");
        // tile kt+1 must be landed for ALL waves after this barrier
        if (kt < NTT - 2)       { asm volatile("s_waitcnt vmcnt(4)" ::: "memory"); }
        else if (kt == NTT - 2) { asm volatile("s_waitcnt vmcnt(0)" ::: "memory"); }
        __builtin_amdgcn_s_barrier();
        asm volatile("" ::: "memory");
        sR = (sR == 2) ? 0 : sR + 1;
        sS = (sS == 2) ? 0 : sS + 1;
    }
#undef STAGE

    // epilogue: C/D layout col=lane&15, row=(lane>>4)*4+j  [m89-verified]
    const int r4 = (l >> 4) * 4;
    const int cl = l & 15;
#pragma unroll
    for (int fm = 0; fm < 4; ++fm) {
#pragma unroll
        for (int fn = 0; fn < 4; ++fn) {
            const int n = bn * 128 + wc * 64 + fn * 16 + cl;
            const float bn_bias = bias[n];
#pragma unroll
            for (int j = 0; j < 4; ++j) {
                const int m = bm * 128 + wr * 64 + fm * 16 + r4 + j;
                float v = acc[fm][fn][j] + bn_bias;
                if (EPI == 1) {
                    if (n < 1024) {
                        out0[(long)m * 1024 + n] = 1.0f / (1.0f + expf(-v));
                    } else {
                        outv[(long)m * 1024 + (n - 1024)] = __float2bfloat16(v);
                    }
                } else if (EPI == 2) {
                    const float sv = tanhf(v);
                    const float g  = gatef_in[(long)m * 1024 + n];
                    out0[(long)m * 1024 + n] = 1.0f - g;
                    out1[(long)m * 1024 + n] = g * sv;
                } else {
                    out0[(long)m * 1024 + n] = x_in[(long)m * 1024 + n] + v;
                }
            }
        }
    }
}

// ---------------- chunked parallel scan: h[t] = a[t]*h[t-1] + b[t] ----------------
__global__ void scan_phase1(const float* __restrict__ af, const float* __restrict__ bfv,
                            float* __restrict__ Ach, float* __restrict__ Bch) {
    int tid = blockIdx.x * 256 + threadIdx.x;   // [chunk][b][d]
    int c = tid >> 12;
    int r = tid & 4095;
    int bi = r >> 10;
    long base = ((long)bi * T_DIM + c * CHL) * D_DIM + (r & 1023);
    float A = 1.0f, Bc = 0.0f;
#pragma unroll 4
    for (int i = 0; i < CHL; ++i) {
        float a = af[base + (long)i * D_DIM];
        float b = bfv[base + (long)i * D_DIM];
        A *= a;
        Bc = a * Bc + b;
    }
    Ach[tid] = A;
    Bch[tid] = Bc;
}

// phase2 fused into phase3: per-thread serial carry over chunk aggregates
// (c = tid>>12 is block-uniform -> no divergence; Ach/Bch are L2-resident 2 MB)
__global__ void scan_phase23(const float* __restrict__ af, const float* __restrict__ bfv,
                             const float* __restrict__ Ach, const float* __restrict__ Bch,
                             bf16* __restrict__ Hs) {
    int tid = blockIdx.x * 256 + threadIdx.x;
    int c = tid >> 12;
    int r = tid & 4095;
    int bi = r >> 10;
    int d  = r & 1023;
    float h = 0.0f;
    for (int j = 0; j < c; ++j)
        h = Ach[j * 4096 + r] * h + Bch[j * 4096 + r];
    long base = ((long)bi * T_DIM + c * CHL) * D_DIM + d;
#pragma unroll 4
    for (int i = 0; i < CHL; ++i) {
        float a = af[base + (long)i * D_DIM];
        float b = bfv[base + (long)i * D_DIM];
        h = a * h + b;
        long m = (long)bi * T_DIM + c * CHL + i;
        Hs[m * 1024 + d] = __float2bfloat16(h);
    }
}

// ---------------- launch ----------------
extern "C" void kernel_launch(void* const* d_in, const int* in_sizes, int n_in,
                              void* d_out, int out_size, void* d_ws, size_t ws_size,
                              hipStream_t stream) {
    const float* x   = (const float*)d_in[0];
    const float* Win = (const float*)d_in[1];
    const float* bin = (const float*)d_in[2];
    const float* Wsm = (const float*)d_in[3];
    const float* bs  = (const float*)d_in[4];
    const float* Wo  = (const float*)d_in[5];
    const float* bo  = (const float*)d_in[6];
    float* out = (float*)d_out;
    char*  ws  = (char*)d_ws;

    bf16*  Xs    = (bf16*)(ws + XS_OFF);   // [M][2048] hi|lo; first 16MB reused as Hs
    bf16*  Wins  = (bf16*)(ws + WIN_OFF);
    bf16*  Wss   = (bf16*)(ws + WSS_OFF);
    bf16*  Wos   = (bf16*)(ws + WOS_OFF);
    float* gatef = (float*)(ws + GATE_OFF);
    bf16*  Vs    = (bf16*)(ws + VS_OFF);   // [M][1024] hi only
    float* af    = (float*)(ws + AF_OFF);
    float* bfv   = (float*)(ws + BF_OFF);
    float* Ach   = (float*)(ws + ACH_OFF);
    float* Bch   = (float*)(ws + BCH_OFF);
    bf16*  Hs    = (bf16*)(ws + XS_OFF);   // [M][1024] (aliases Xs)

    // activation split (hi|lo); merged weight converts (1 dispatch)
    split_kernel<<<(M_DIM * D_DIM / 4 + 255) / 256, 256, 0, stream>>>(x, Xs, (long)M_DIM * D_DIM / 4);
    wconv_kernel<<<4096, 256, 0, stream>>>(Win, Wsm, Wo, Wins, Wss, Wos);

    // GEMM1: gv = x @ W_in^T ; gate/val epilogue (K'=2048: hi+lo activations)
    dim3 g1(M_DIM / 128, 2048 / 128);
    gemm128<1, 64, 2048><<<g1, 256, 0, stream>>>(Xs, Wins, bin, nullptr, nullptr, gatef, nullptr, Vs);

    // GEMM2: sv = tanh(val @ W_s^T) ; a,b epilogue (K'=1024: bf16 val)
    dim3 g2(M_DIM / 128, 1024 / 128);
    gemm128<2, 32, 1024><<<g2, 256, 0, stream>>>(Vs, Wss, bs, gatef, nullptr, af, bfv, nullptr);

    // scan: h[t] = a[t]*h[t-1] + b[t]
    scan_phase1 <<<NCH * 4096 / 256, 256, 0, stream>>>(af, bfv, Ach, Bch);
    scan_phase23<<<NCH * 4096 / 256, 256, 0, stream>>>(af, bfv, Ach, Bch, Hs);

    // GEMM3: out = x + h @ W_o^T + b_o (K'=1024: bf16 h)
    gemm128<3, 32, 1024><<<g2, 256, 0, stream>>>(Hs, Wos, bo, nullptr, x, out, nullptr, nullptr);
}